// Round 1
// baseline (1012.548 us; speedup 1.0000x reference)
//
#include <hip/hip_runtime.h>

#define CH 64

// ---- deg / dinv -----------------------------------------------------------

__global__ __launch_bounds__(256) void k_init_deg(float* deg, int n) {
    int i = blockIdx.x * blockDim.x + threadIdx.x;
    if (i < n) deg[i] = 1.0f;  // self-loop contribution
}

__global__ __launch_bounds__(256) void k_count_deg(const int* __restrict__ dst,
                                                   float* __restrict__ deg, int E) {
    int i = blockIdx.x * blockDim.x + threadIdx.x;
    int stride = gridDim.x * blockDim.x;
    for (int e = i; e < E; e += stride)
        atomicAdd(&deg[dst[e]], 1.0f);
}

__global__ __launch_bounds__(256) void k_dinv(float* deg, int n) {
    int i = blockIdx.x * blockDim.x + threadIdx.x;
    if (i < n) deg[i] = 1.0f / sqrtf(deg[i]);  // deg >= 1 always (self-loops)
}

// ---- GEMM: wave-per-node, W in LDS, x-row broadcast via shuffle -----------
// out h[node][c] = sum_k in[node][k] * W[k][c]; also writes
// agginit[node][c] = h * dinv[node]^2 (the self-loop message), so the
// scatter kernel needs no zero-init pass.
// BIAS_RELU: apply (in + bias) then relu on load (layer-2 reads layer-1 agg).
// NOTE: no __restrict__ on in/agginit — for layer 2 they alias (in-place).

template <bool BIAS_RELU>
__global__ __launch_bounds__(256) void k_gemm64(const float* in, const float* W,
                                                const float* bias, const float* dinv,
                                                float* hlin, float* agginit, int n) {
    __shared__ float Ws[CH * CH];
    for (int i = threadIdx.x; i < CH * CH; i += blockDim.x) Ws[i] = W[i];
    __syncthreads();

    int lane = threadIdx.x & 63;
    int wid  = (blockIdx.x * blockDim.x + threadIdx.x) >> 6;
    int nw   = (gridDim.x * blockDim.x) >> 6;

    for (int node = wid; node < n; node += nw) {
        float v = in[(size_t)node * CH + lane];
        if (BIAS_RELU) v = fmaxf(v + bias[lane], 0.0f);
        float acc = 0.0f;
#pragma unroll
        for (int k = 0; k < CH; ++k) {
            float xk = __shfl(v, k, 64);          // broadcast x[node][k]
            acc = fmaf(xk, Ws[k * CH + lane], acc);
        }
        hlin[(size_t)node * CH + lane] = acc;
        float d = dinv[node];
        agginit[(size_t)node * CH + lane] = acc * d * d;
    }
}

// ---- edge scatter: one wave per edge, lane = channel ----------------------

__global__ __launch_bounds__(256) void k_scatter(const int* __restrict__ srcs,
                                                 const int* __restrict__ dsts,
                                                 const float* __restrict__ dinv,
                                                 const float* __restrict__ hlin,
                                                 float* __restrict__ agg, int E) {
    int lane = threadIdx.x & 63;
    int wid  = (blockIdx.x * blockDim.x + threadIdx.x) >> 6;
    int nw   = (gridDim.x * blockDim.x) >> 6;

    for (int e = wid; e < E; e += nw) {
        int s = srcs[e];
        int d = dsts[e];
        float norm = dinv[s] * dinv[d];
        float m = hlin[(size_t)s * CH + lane] * norm;
        atomicAdd(&agg[(size_t)d * CH + lane], m);
    }
}

// ---- head: (agg + b2) @ Wl + bl -> sigmoid --------------------------------

__global__ __launch_bounds__(256) void k_head(const float* __restrict__ agg,
                                              const float* __restrict__ b2,
                                              const float* __restrict__ Wl,
                                              const float* __restrict__ bl,
                                              float* __restrict__ out, int n) {
    int lane = threadIdx.x & 63;
    int wid  = (blockIdx.x * blockDim.x + threadIdx.x) >> 6;
    int nw   = (gridDim.x * blockDim.x) >> 6;

    for (int node = wid; node < n; node += nw) {
        float v = (agg[(size_t)node * CH + lane] + b2[lane]) * Wl[lane];
#pragma unroll
        for (int off = 32; off > 0; off >>= 1) v += __shfl_xor(v, off, 64);
        if (lane == 0) out[node] = 1.0f / (1.0f + expf(-(v + bl[0])));
    }
}

// ---- launch ---------------------------------------------------------------

extern "C" void kernel_launch(void* const* d_in, const int* in_sizes, int n_in,
                              void* d_out, int out_size, void* d_ws, size_t ws_size,
                              hipStream_t stream) {
    const float* x   = (const float*)d_in[0];
    const int*   ei  = (const int*)d_in[1];   // [2, E] row-major
    const float* W1  = (const float*)d_in[2];
    const float* b1  = (const float*)d_in[3];
    const float* W2  = (const float*)d_in[4];
    const float* b2  = (const float*)d_in[5];
    const float* Wl  = (const float*)d_in[6];
    const float* bl  = (const float*)d_in[7];
    float*       out = (float*)d_out;

    const int N = in_sizes[0] / CH;
    const int E = in_sizes[1] / 2;
    const int* src = ei;
    const int* dst = ei + E;

    float* ws   = (float*)d_ws;
    float* dinv = ws;                                   // N floats (deg, then dinv)
    float* A    = ws + (((size_t)N + 255) & ~(size_t)255);  // N*64: hlin
    float* B    = A + (size_t)N * CH;                   // N*64: agg

    const int TB = 256;
    const int nblk_n  = (N + TB - 1) / TB;
    const int GRID    = 2048;  // grid-stride: 8 blocks/CU, 32 waves/CU

    k_init_deg<<<nblk_n, TB, 0, stream>>>(dinv, N);
    k_count_deg<<<GRID, TB, 0, stream>>>(dst, dinv, E);
    k_dinv<<<nblk_n, TB, 0, stream>>>(dinv, N);

    // Layer 1: A = x@W1 ; B = A * dinv^2 (self-loop init) ; then edge scatter
    k_gemm64<false><<<GRID, TB, 0, stream>>>(x, W1, nullptr, dinv, A, B, N);
    k_scatter<<<GRID, TB, 0, stream>>>(src, dst, dinv, A, B, E);

    // Layer 2: read B (+b1, relu), A = h1@W2 ; B = A * dinv^2 ; edge scatter
    k_gemm64<true><<<GRID, TB, 0, stream>>>(B, W2, b1, dinv, A, B, N);
    k_scatter<<<GRID, TB, 0, stream>>>(src, dst, dinv, A, B, E);

    // Head
    k_head<<<GRID, TB, 0, stream>>>(B, b2, Wl, bl, out, N);
}

// Round 2
// 847.417 us; speedup vs baseline: 1.1949x; 1.1949x over previous
//
#include <hip/hip_runtime.h>

#define CH 64

// ---- CSR build ------------------------------------------------------------

__global__ __launch_bounds__(256) void k_zero(int* p, int n) {
    int i = blockIdx.x * blockDim.x + threadIdx.x;
    if (i < n) p[i] = 0;
}

__global__ __launch_bounds__(256) void k_count(const int* __restrict__ dst,
                                               int* __restrict__ cnt, int E) {
    int i = blockIdx.x * blockDim.x + threadIdx.x;
    int st = gridDim.x * blockDim.x;
    for (int e = i; e < E; e += st) atomicAdd(&cnt[dst[e]], 1);
}

// Single-block exclusive scan of cnt -> row_ptr (+ cursor copy + dinv).
// n=100K, 1024 threads, each handles a contiguous chunk.
__global__ __launch_bounds__(1024) void k_scan(const int* __restrict__ cnt,
                                               int* __restrict__ row_ptr,
                                               int* __restrict__ cursor,
                                               float* __restrict__ dinv, int n) {
    __shared__ int part[1024];
    int t = threadIdx.x;
    int chunk = (n + 1023) / 1024;
    int beg = t * chunk;
    int end = min(beg + chunk, n);
    int s = 0;
    for (int i = beg; i < end; ++i) s += cnt[i];
    part[t] = s;
    __syncthreads();
    for (int off = 1; off < 1024; off <<= 1) {
        int v = (t >= off) ? part[t - off] : 0;
        __syncthreads();
        part[t] += v;
        __syncthreads();
    }
    int run = (t == 0) ? 0 : part[t - 1];   // exclusive prefix of this chunk
    for (int i = beg; i < end; ++i) {
        row_ptr[i] = run;
        cursor[i]  = run;
        int c = cnt[i];
        run += c;
        dinv[i] = rsqrtf((float)(c + 1));   // +1 self-loop; deg>=1 always
    }
    if (t == 1023) row_ptr[n] = part[1023]; // = E
}

__global__ __launch_bounds__(256) void k_fill(const int* __restrict__ src,
                                              const int* __restrict__ dst,
                                              int* __restrict__ cursor,
                                              int* __restrict__ col, int E) {
    int i = blockIdx.x * blockDim.x + threadIdx.x;
    int st = gridDim.x * blockDim.x;
    for (int e = i; e < E; e += st) {
        int p = atomicAdd(&cursor[dst[e]], 1);
        col[p] = src[e];
    }
}

// ---- GEMM: wave-per-node, W in LDS, x-row broadcast via shuffle -----------
// Writes hs[node][c] = ((in+bias relu?) @ W)[node][c] * dinv[node].

template <bool BIAS_RELU>
__global__ __launch_bounds__(256) void k_gemm64(const float* in, const float* __restrict__ W,
                                                const float* __restrict__ bias,
                                                const float* __restrict__ dinv,
                                                float* hs, int n) {
    __shared__ float Ws[CH * CH];
    for (int i = threadIdx.x; i < CH * CH; i += blockDim.x) Ws[i] = W[i];
    __syncthreads();

    int lane = threadIdx.x & 63;
    int wid  = (blockIdx.x * blockDim.x + threadIdx.x) >> 6;
    int nw   = (gridDim.x * blockDim.x) >> 6;

    for (int node = wid; node < n; node += nw) {
        float v = in[(size_t)node * CH + lane];
        if (BIAS_RELU) v = fmaxf(v + bias[lane], 0.0f);
        float acc = 0.0f;
#pragma unroll
        for (int k = 0; k < CH; ++k)
            acc = fmaf(__shfl(v, k, 64), Ws[k * CH + lane], acc);
        hs[(size_t)node * CH + lane] = acc * dinv[node];
    }
}

// ---- CSR gather: agg[n] = dinv[n] * (hs[n] + sum_{s->n} hs[s]) ------------

__global__ __launch_bounds__(256) void k_gather(const int* __restrict__ row_ptr,
                                                const int* __restrict__ col,
                                                const float* __restrict__ hs,
                                                const float* __restrict__ dinv,
                                                float* __restrict__ agg, int n) {
    int lane = threadIdx.x & 63;
    int wid  = (blockIdx.x * blockDim.x + threadIdx.x) >> 6;
    int nw   = (gridDim.x * blockDim.x) >> 6;

    for (int node = wid; node < n; node += nw) {
        int beg = row_ptr[node];
        int end = row_ptr[node + 1];
        float acc = hs[(size_t)node * CH + lane];  // self-loop term
        int e = beg;
        for (; e + 4 <= end; e += 4) {             // 4-unrolled: overlap loads
            int s0 = col[e], s1 = col[e + 1], s2 = col[e + 2], s3 = col[e + 3];
            float a0 = hs[(size_t)s0 * CH + lane];
            float a1 = hs[(size_t)s1 * CH + lane];
            float a2 = hs[(size_t)s2 * CH + lane];
            float a3 = hs[(size_t)s3 * CH + lane];
            acc += a0; acc += a1; acc += a2; acc += a3;
        }
        for (; e < end; ++e)
            acc += hs[(size_t)col[e] * CH + lane];
        agg[(size_t)node * CH + lane] = acc * dinv[node];
    }
}

// ---- head: (agg + b2) @ Wl + bl -> sigmoid --------------------------------

__global__ __launch_bounds__(256) void k_head(const float* __restrict__ agg,
                                              const float* __restrict__ b2,
                                              const float* __restrict__ Wl,
                                              const float* __restrict__ bl,
                                              float* __restrict__ out, int n) {
    int lane = threadIdx.x & 63;
    int wid  = (blockIdx.x * blockDim.x + threadIdx.x) >> 6;
    int nw   = (gridDim.x * blockDim.x) >> 6;

    for (int node = wid; node < n; node += nw) {
        float v = (agg[(size_t)node * CH + lane] + b2[lane]) * Wl[lane];
#pragma unroll
        for (int off = 32; off > 0; off >>= 1) v += __shfl_xor(v, off, 64);
        if (lane == 0) out[node] = 1.0f / (1.0f + expf(-(v + bl[0])));
    }
}

// ---- launch ---------------------------------------------------------------

extern "C" void kernel_launch(void* const* d_in, const int* in_sizes, int n_in,
                              void* d_out, int out_size, void* d_ws, size_t ws_size,
                              hipStream_t stream) {
    const float* x   = (const float*)d_in[0];
    const int*   ei  = (const int*)d_in[1];   // [2, E] row-major
    const float* W1  = (const float*)d_in[2];
    const float* b1  = (const float*)d_in[3];
    const float* W2  = (const float*)d_in[4];
    const float* b2  = (const float*)d_in[5];
    const float* Wl  = (const float*)d_in[6];
    const float* bl  = (const float*)d_in[7];
    float*       out = (float*)d_out;

    const int N = in_sizes[0] / CH;
    const int E = in_sizes[1] / 2;
    const int* src = ei;
    const int* dst = ei + E;

    const size_t Npad = ((size_t)N + 511) & ~(size_t)511;

    float* A       = (float*)d_ws;            // N*CH  (hs)
    float* B       = A + (size_t)N * CH;      // N*CH  (agg)
    float* dinv    = B + (size_t)N * CH;      // N
    int*   cnt     = (int*)(dinv + Npad);     // N
    int*   row_ptr = cnt + Npad;              // N+1
    int*   cursor  = row_ptr + Npad;          // N
    int*   col     = cursor + Npad;           // E

    const int TB = 256;
    const int nblk_n = (N + TB - 1) / TB;
    const int GRID   = 2048;

    // CSR build (per call; no persistent state allowed)
    k_zero<<<nblk_n, TB, 0, stream>>>(cnt, N);
    k_count<<<GRID, TB, 0, stream>>>(dst, cnt, E);
    k_scan<<<1, 1024, 0, stream>>>(cnt, row_ptr, cursor, dinv, N);
    k_fill<<<GRID, TB, 0, stream>>>(src, dst, cursor, col, E);

    // Layer 1
    k_gemm64<false><<<GRID, TB, 0, stream>>>(x, W1, nullptr, dinv, A, N);
    k_gather<<<GRID, TB, 0, stream>>>(row_ptr, col, A, dinv, B, N);

    // Layer 2 (reads B with +b1/relu, writes A; gather A -> B)
    k_gemm64<true><<<GRID, TB, 0, stream>>>(B, W2, b1, dinv, A, N);
    k_gather<<<GRID, TB, 0, stream>>>(row_ptr, col, A, dinv, B, N);

    // Head
    k_head<<<GRID, TB, 0, stream>>>(B, b2, Wl, bl, out, N);
}

// Round 3
// 588.677 us; speedup vs baseline: 1.7200x; 1.4395x over previous
//
#include <hip/hip_runtime.h>

#define CH 64
#define SCAN_TPB 256
#define SCAN_PER_THREAD 4
#define SCAN_CHUNK (SCAN_TPB * SCAN_PER_THREAD)  // 1024 elements per block

// ---- CSR build ------------------------------------------------------------

__global__ __launch_bounds__(256) void k_zero(int* p, int n) {
    int i = blockIdx.x * blockDim.x + threadIdx.x;
    if (i < n) p[i] = 0;
}

__global__ __launch_bounds__(256) void k_count(const int* __restrict__ dst,
                                               int* __restrict__ cnt, int E) {
    int i = blockIdx.x * blockDim.x + threadIdx.x;
    int st = gridDim.x * blockDim.x;
    for (int e = i; e < E; e += st) atomicAdd(&cnt[dst[e]], 1);
}

// Hierarchical scan, stage 1: per-block sums of 1024-element chunks.
__global__ __launch_bounds__(SCAN_TPB) void k_blocksum(const int* __restrict__ cnt,
                                                       int* __restrict__ bsum, int n) {
    __shared__ int red[SCAN_TPB];
    int base = blockIdx.x * SCAN_CHUNK + threadIdx.x * SCAN_PER_THREAD;
    int s = 0;
#pragma unroll
    for (int j = 0; j < SCAN_PER_THREAD; ++j) {
        int i = base + j;
        if (i < n) s += cnt[i];
    }
    red[threadIdx.x] = s;
    __syncthreads();
    for (int off = SCAN_TPB / 2; off > 0; off >>= 1) {
        if (threadIdx.x < off) red[threadIdx.x] += red[threadIdx.x + off];
        __syncthreads();
    }
    if (threadIdx.x == 0) bsum[blockIdx.x] = red[0];
}

// Stage 2: single small block scans the block sums (B <= 1024).
__global__ __launch_bounds__(1024) void k_scanbsum(const int* __restrict__ bsum,
                                                   int* __restrict__ boff,
                                                   int* __restrict__ row_ptr_n, int B) {
    __shared__ int sh[1024];
    int t = threadIdx.x;
    int v = (t < B) ? bsum[t] : 0;
    sh[t] = v;
    __syncthreads();
    for (int off = 1; off < 1024; off <<= 1) {
        int u = (t >= off) ? sh[t - off] : 0;
        __syncthreads();
        sh[t] += u;
        __syncthreads();
    }
    if (t < B) boff[t] = sh[t] - v;          // exclusive block offset
    if (t == 1023) *row_ptr_n = sh[1023];    // total = E
}

// Stage 3: re-scan each chunk locally, add block offset, write outputs.
__global__ __launch_bounds__(SCAN_TPB) void k_scanwrite(const int* __restrict__ cnt,
                                                        const int* __restrict__ boff,
                                                        int* __restrict__ row_ptr,
                                                        int* __restrict__ cursor,
                                                        float* __restrict__ dinv, int n) {
    __shared__ int sh[SCAN_TPB];
    int t = threadIdx.x;
    int base = blockIdx.x * SCAN_CHUNK + t * SCAN_PER_THREAD;
    int c[SCAN_PER_THREAD];
    int s = 0;
#pragma unroll
    for (int j = 0; j < SCAN_PER_THREAD; ++j) {
        int i = base + j;
        c[j] = (i < n) ? cnt[i] : 0;
        s += c[j];
    }
    sh[t] = s;
    __syncthreads();
    for (int off = 1; off < SCAN_TPB; off <<= 1) {
        int u = (t >= off) ? sh[t - off] : 0;
        __syncthreads();
        sh[t] += u;
        __syncthreads();
    }
    int run = boff[blockIdx.x] + sh[t] - s;  // exclusive prefix for this thread
#pragma unroll
    for (int j = 0; j < SCAN_PER_THREAD; ++j) {
        int i = base + j;
        if (i < n) {
            row_ptr[i] = run;
            cursor[i]  = run;
            run += c[j];
            dinv[i] = rsqrtf((float)(c[j] + 1));  // +1 self-loop
        }
    }
}

__global__ __launch_bounds__(256) void k_fill(const int* __restrict__ src,
                                              const int* __restrict__ dst,
                                              int* __restrict__ cursor,
                                              int* __restrict__ col, int E) {
    int i = blockIdx.x * blockDim.x + threadIdx.x;
    int st = gridDim.x * blockDim.x;
    for (int e = i; e < E; e += st) {
        int p = atomicAdd(&cursor[dst[e]], 1);
        col[p] = src[e];
    }
}

// ---- GEMM: wave-per-node, W in LDS, x-row broadcast via shuffle -----------
// Writes hs[node][c] = ((in+bias relu?) @ W)[node][c] * dinv[node].

template <bool BIAS_RELU>
__global__ __launch_bounds__(256) void k_gemm64(const float* in, const float* __restrict__ W,
                                                const float* __restrict__ bias,
                                                const float* __restrict__ dinv,
                                                float* hs, int n) {
    __shared__ float Ws[CH * CH];
    for (int i = threadIdx.x; i < CH * CH; i += blockDim.x) Ws[i] = W[i];
    __syncthreads();

    int lane = threadIdx.x & 63;
    int wid  = (blockIdx.x * blockDim.x + threadIdx.x) >> 6;
    int nw   = (gridDim.x * blockDim.x) >> 6;

    for (int node = wid; node < n; node += nw) {
        float v = in[(size_t)node * CH + lane];
        if (BIAS_RELU) v = fmaxf(v + bias[lane], 0.0f);
        float acc = 0.0f;
#pragma unroll
        for (int k = 0; k < CH; ++k)
            acc = fmaf(__shfl(v, k, 64), Ws[k * CH + lane], acc);
        hs[(size_t)node * CH + lane] = acc * dinv[node];
    }
}

// ---- CSR gather: agg[n] = dinv[n] * (hs[n] + sum_{s->n} hs[s]) ------------

__global__ __launch_bounds__(256) void k_gather(const int* __restrict__ row_ptr,
                                                const int* __restrict__ col,
                                                const float* __restrict__ hs,
                                                const float* __restrict__ dinv,
                                                float* __restrict__ agg, int n) {
    int lane = threadIdx.x & 63;
    int wid  = (blockIdx.x * blockDim.x + threadIdx.x) >> 6;
    int nw   = (gridDim.x * blockDim.x) >> 6;

    for (int node = wid; node < n; node += nw) {
        int beg = row_ptr[node];
        int end = row_ptr[node + 1];
        float acc = hs[(size_t)node * CH + lane];  // self-loop term
        int e = beg;
        for (; e + 4 <= end; e += 4) {             // 4-unrolled: overlap loads
            int s0 = col[e], s1 = col[e + 1], s2 = col[e + 2], s3 = col[e + 3];
            float a0 = hs[(size_t)s0 * CH + lane];
            float a1 = hs[(size_t)s1 * CH + lane];
            float a2 = hs[(size_t)s2 * CH + lane];
            float a3 = hs[(size_t)s3 * CH + lane];
            acc += a0; acc += a1; acc += a2; acc += a3;
        }
        for (; e < end; ++e)
            acc += hs[(size_t)col[e] * CH + lane];
        agg[(size_t)node * CH + lane] = acc * dinv[node];
    }
}

// ---- head: (agg + b2) @ Wl + bl -> sigmoid --------------------------------

__global__ __launch_bounds__(256) void k_head(const float* __restrict__ agg,
                                              const float* __restrict__ b2,
                                              const float* __restrict__ Wl,
                                              const float* __restrict__ bl,
                                              float* __restrict__ out, int n) {
    int lane = threadIdx.x & 63;
    int wid  = (blockIdx.x * blockDim.x + threadIdx.x) >> 6;
    int nw   = (gridDim.x * blockDim.x) >> 6;

    for (int node = wid; node < n; node += nw) {
        float v = (agg[(size_t)node * CH + lane] + b2[lane]) * Wl[lane];
#pragma unroll
        for (int off = 32; off > 0; off >>= 1) v += __shfl_xor(v, off, 64);
        if (lane == 0) out[node] = 1.0f / (1.0f + expf(-(v + bl[0])));
    }
}

// ---- launch ---------------------------------------------------------------

extern "C" void kernel_launch(void* const* d_in, const int* in_sizes, int n_in,
                              void* d_out, int out_size, void* d_ws, size_t ws_size,
                              hipStream_t stream) {
    const float* x   = (const float*)d_in[0];
    const int*   ei  = (const int*)d_in[1];   // [2, E] row-major
    const float* W1  = (const float*)d_in[2];
    const float* b1  = (const float*)d_in[3];
    const float* W2  = (const float*)d_in[4];
    const float* b2  = (const float*)d_in[5];
    const float* Wl  = (const float*)d_in[6];
    const float* bl  = (const float*)d_in[7];
    float*       out = (float*)d_out;

    const int N = in_sizes[0] / CH;
    const int E = in_sizes[1] / 2;
    const int* src = ei;
    const int* dst = ei + E;

    const size_t Npad = ((size_t)N + 511) & ~(size_t)511;

    float* A       = (float*)d_ws;            // N*CH  (hs)
    float* B       = A + (size_t)N * CH;      // N*CH  (agg)
    float* dinv    = B + (size_t)N * CH;      // N
    int*   cnt     = (int*)(dinv + Npad);     // N
    int*   row_ptr = cnt + Npad;              // N+1
    int*   cursor  = row_ptr + Npad;          // N
    int*   col     = cursor + Npad;           // E
    int*   bsum    = col + (((size_t)E + 511) & ~(size_t)511);  // <=1024
    int*   boff    = bsum + 1024;                                // <=1024

    const int TB = 256;
    const int nblk_n = (N + TB - 1) / TB;
    const int GRID   = 2048;
    const int NSCAN  = (N + SCAN_CHUNK - 1) / SCAN_CHUNK;  // 98 blocks

    // CSR build (per call; no persistent state allowed)
    k_zero<<<nblk_n, TB, 0, stream>>>(cnt, N);
    k_count<<<GRID, TB, 0, stream>>>(dst, cnt, E);
    k_blocksum<<<NSCAN, SCAN_TPB, 0, stream>>>(cnt, bsum, N);
    k_scanbsum<<<1, 1024, 0, stream>>>(bsum, boff, row_ptr + N, NSCAN);
    k_scanwrite<<<NSCAN, SCAN_TPB, 0, stream>>>(cnt, boff, row_ptr, cursor, dinv, N);
    k_fill<<<GRID, TB, 0, stream>>>(src, dst, cursor, col, E);

    // Layer 1
    k_gemm64<false><<<GRID, TB, 0, stream>>>(x, W1, nullptr, dinv, A, N);
    k_gather<<<GRID, TB, 0, stream>>>(row_ptr, col, A, dinv, B, N);

    // Layer 2 (reads B with +b1/relu, writes A; gather A -> B)
    k_gemm64<true><<<GRID, TB, 0, stream>>>(B, W2, b1, dinv, A, N);
    k_gather<<<GRID, TB, 0, stream>>>(row_ptr, col, A, dinv, B, N);

    // Head
    k_head<<<GRID, TB, 0, stream>>>(B, b2, Wl, bl, out, N);
}

// Round 4
// 426.086 us; speedup vs baseline: 2.3764x; 1.3816x over previous
//
#include <hip/hip_runtime.h>

#define CH 64
#define NBUCK 1024        // buckets = dst >> 7 (128 nodes/bucket); needs N <= 131072
#define BSHIFT 7
#define BMASK 127
#define NBLK_P 128        // partition blocks; must match between k_hist/k_partition

// ---- CSR build: scatter-free two-level bucket sort ------------------------

// Stage 1: per-block LDS histogram of dst buckets.
__global__ __launch_bounds__(256) void k_hist(const int* __restrict__ dst,
                                              int* __restrict__ blkhist, int E) {
    __shared__ int h[NBUCK];
    for (int i = threadIdx.x; i < NBUCK; i += blockDim.x) h[i] = 0;
    __syncthreads();
    int chunk = (E + NBLK_P - 1) / NBLK_P;
    int beg = blockIdx.x * chunk;
    int end = min(beg + chunk, E);
    for (int e = beg + threadIdx.x; e < end; e += blockDim.x)
        atomicAdd(&h[dst[e] >> BSHIFT], 1);
    __syncthreads();
    for (int i = threadIdx.x; i < NBUCK; i += blockDim.x)
        blkhist[blockIdx.x * NBUCK + i] = h[i];
}

// Stage 2: one block: bucket totals -> exclusive bucket_base, and
// per-(block,bucket) exclusive offsets. Also writes row_ptr[N] = E.
__global__ __launch_bounds__(1024) void k_scan2(const int* __restrict__ blkhist,
                                                int* __restrict__ off,
                                                int* __restrict__ bbase,
                                                int* __restrict__ row_ptr, int n) {
    __shared__ int sh[NBUCK];
    int t = threadIdx.x;
    int tot = 0;
    for (int b = 0; b < NBLK_P; ++b) tot += blkhist[b * NBUCK + t];
    sh[t] = tot;
    __syncthreads();
    for (int o = 1; o < NBUCK; o <<= 1) {
        int v = (t >= o) ? sh[t - o] : 0;
        __syncthreads();
        sh[t] += v;
        __syncthreads();
    }
    int excl = sh[t] - tot;
    bbase[t] = excl;
    if (t == NBUCK - 1) {
        bbase[NBUCK] = sh[NBUCK - 1];       // = E
        row_ptr[n]   = sh[NBUCK - 1];       // CSR terminator
    }
    int run = excl;
    for (int b = 0; b < NBLK_P; ++b) {
        off[b * NBUCK + t] = run;
        run += blkhist[b * NBUCK + t];
    }
}

// Stage 3: permute edges into bucket order; packed (dlow<<17)|src (4B).
// All cursor atomics are in LDS; global writes are per-(block,bucket)
// contiguous runs.
__global__ __launch_bounds__(256) void k_partition(const int* __restrict__ src,
                                                   const int* __restrict__ dst,
                                                   const int* __restrict__ off,
                                                   unsigned int* __restrict__ ebuf, int E) {
    __shared__ int cur[NBUCK];
    for (int i = threadIdx.x; i < NBUCK; i += blockDim.x)
        cur[i] = off[blockIdx.x * NBUCK + i];
    __syncthreads();
    int chunk = (E + NBLK_P - 1) / NBLK_P;
    int beg = blockIdx.x * chunk;
    int end = min(beg + chunk, E);
    for (int e = beg + threadIdx.x; e < end; e += blockDim.x) {
        int s = src[e];
        int d = dst[e];
        int p = atomicAdd(&cur[d >> BSHIFT], 1);
        ebuf[p] = ((unsigned int)(d & BMASK) << 17) | (unsigned int)s;
    }
}

// Stage 4: per-bucket counting sort (128 node slots) -> row_ptr, dinv, col.
__global__ __launch_bounds__(128) void k_bucket_csr(const unsigned int* __restrict__ ebuf,
                                                    const int* __restrict__ bbase,
                                                    int* __restrict__ row_ptr,
                                                    float* __restrict__ dinv,
                                                    int* __restrict__ col, int n) {
    __shared__ int cnt[128];
    __shared__ int cur[128];
    int t = threadIdx.x;
    int k = blockIdx.x;
    int e0 = bbase[k], e1 = bbase[k + 1];
    cnt[t] = 0;
    __syncthreads();
    for (int e = e0 + t; e < e1; e += 128)
        atomicAdd(&cnt[ebuf[e] >> 17], 1);
    __syncthreads();
    int c = cnt[t];
    __shared__ int sc[128];
    sc[t] = c;
    __syncthreads();
    for (int o = 1; o < 128; o <<= 1) {
        int v = (t >= o) ? sc[t - o] : 0;
        __syncthreads();
        sc[t] += v;
        __syncthreads();
    }
    int excl = sc[t] - c;
    int node = (k << BSHIFT) + t;
    if (node < n) {
        row_ptr[node] = e0 + excl;
        dinv[node] = rsqrtf((float)(c + 1));   // +1 self-loop
    }
    cur[t] = e0 + excl;
    __syncthreads();
    for (int e = e0 + t; e < e1; e += 128) {
        unsigned int u = ebuf[e];
        int p = atomicAdd(&cur[u >> 17], 1);
        col[p] = (int)(u & 0x1FFFFu);
    }
}

// ---- GEMM: wave-per-node, W in LDS, x-row broadcast via shuffle -----------
// Writes hs[node][c] = (in @ W)[node][c] * dinv[node].

__global__ __launch_bounds__(256) void k_gemm64(const float* __restrict__ in,
                                                const float* __restrict__ W,
                                                const float* __restrict__ dinv,
                                                float* __restrict__ hs, int n) {
    __shared__ float Ws[CH * CH];
    for (int i = threadIdx.x; i < CH * CH; i += blockDim.x) Ws[i] = W[i];
    __syncthreads();

    int lane = threadIdx.x & 63;
    int wid  = (blockIdx.x * blockDim.x + threadIdx.x) >> 6;
    int nw   = (gridDim.x * blockDim.x) >> 6;

    for (int node = wid; node < n; node += nw) {
        float v = in[(size_t)node * CH + lane];
        float acc = 0.0f;
#pragma unroll
        for (int k = 0; k < CH; ++k)
            acc = fmaf(__shfl(v, k, 64), Ws[k * CH + lane], acc);
        hs[(size_t)node * CH + lane] = acc * dinv[node];
    }
}

// ---- fused: gather(agg1) + bias + relu + GEMM(W2) -> hs2 ------------------

__global__ __launch_bounds__(256) void k_gather_gemm(const int* __restrict__ row_ptr,
                                                     const int* __restrict__ col,
                                                     const float* __restrict__ hs,
                                                     const float* __restrict__ dinv,
                                                     const float* __restrict__ W,
                                                     const float* __restrict__ bias,
                                                     float* __restrict__ hs2, int n) {
    __shared__ float Ws[CH * CH];
    for (int i = threadIdx.x; i < CH * CH; i += blockDim.x) Ws[i] = W[i];
    __syncthreads();

    int lane = threadIdx.x & 63;
    int wid  = (blockIdx.x * blockDim.x + threadIdx.x) >> 6;
    int nw   = (gridDim.x * blockDim.x) >> 6;

    for (int node = wid; node < n; node += nw) {
        int beg = row_ptr[node];
        int end = row_ptr[node + 1];
        float acc = hs[(size_t)node * CH + lane];  // self-loop term
        int e = beg;
        for (; e + 4 <= end; e += 4) {
            int s0 = col[e], s1 = col[e + 1], s2 = col[e + 2], s3 = col[e + 3];
            float a0 = hs[(size_t)s0 * CH + lane];
            float a1 = hs[(size_t)s1 * CH + lane];
            float a2 = hs[(size_t)s2 * CH + lane];
            float a3 = hs[(size_t)s3 * CH + lane];
            acc += a0; acc += a1; acc += a2; acc += a3;
        }
        for (; e < end; ++e)
            acc += hs[(size_t)col[e] * CH + lane];
        float d = dinv[node];
        float v = fmaxf(acc * d + bias[lane], 0.0f);   // h1 row (relu(agg1+b1))
        float acc2 = 0.0f;
#pragma unroll
        for (int k = 0; k < CH; ++k)
            acc2 = fmaf(__shfl(v, k, 64), Ws[k * CH + lane], acc2);
        hs2[(size_t)node * CH + lane] = acc2 * d;
    }
}

// ---- fused: gather(agg2) + head: sigmoid((agg2+b2)@Wl + bl) ---------------

__global__ __launch_bounds__(256) void k_gather_head(const int* __restrict__ row_ptr,
                                                     const int* __restrict__ col,
                                                     const float* __restrict__ hs,
                                                     const float* __restrict__ dinv,
                                                     const float* __restrict__ b2,
                                                     const float* __restrict__ Wl,
                                                     const float* __restrict__ bl,
                                                     float* __restrict__ out, int n) {
    int lane = threadIdx.x & 63;
    int wid  = (blockIdx.x * blockDim.x + threadIdx.x) >> 6;
    int nw   = (gridDim.x * blockDim.x) >> 6;

    for (int node = wid; node < n; node += nw) {
        int beg = row_ptr[node];
        int end = row_ptr[node + 1];
        float acc = hs[(size_t)node * CH + lane];
        int e = beg;
        for (; e + 4 <= end; e += 4) {
            int s0 = col[e], s1 = col[e + 1], s2 = col[e + 2], s3 = col[e + 3];
            float a0 = hs[(size_t)s0 * CH + lane];
            float a1 = hs[(size_t)s1 * CH + lane];
            float a2 = hs[(size_t)s2 * CH + lane];
            float a3 = hs[(size_t)s3 * CH + lane];
            acc += a0; acc += a1; acc += a2; acc += a3;
        }
        for (; e < end; ++e)
            acc += hs[(size_t)col[e] * CH + lane];
        float v = (acc * dinv[node] + b2[lane]) * Wl[lane];
#pragma unroll
        for (int off = 32; off > 0; off >>= 1) v += __shfl_xor(v, off, 64);
        if (lane == 0) out[node] = 1.0f / (1.0f + expf(-(v + bl[0])));
    }
}

// ---- launch ---------------------------------------------------------------

extern "C" void kernel_launch(void* const* d_in, const int* in_sizes, int n_in,
                              void* d_out, int out_size, void* d_ws, size_t ws_size,
                              hipStream_t stream) {
    const float* x   = (const float*)d_in[0];
    const int*   ei  = (const int*)d_in[1];   // [2, E] row-major
    const float* W1  = (const float*)d_in[2];
    const float* b1  = (const float*)d_in[3];
    const float* W2  = (const float*)d_in[4];
    const float* b2  = (const float*)d_in[5];
    const float* Wl  = (const float*)d_in[6];
    const float* bl  = (const float*)d_in[7];
    float*       out = (float*)d_out;

    const int N = in_sizes[0] / CH;
    const int E = in_sizes[1] / 2;
    const int* src = ei;
    const int* dst = ei + E;

    const size_t Npad = ((size_t)N + 511) & ~(size_t)511;
    const size_t Epad = ((size_t)E + 511) & ~(size_t)511;

    float* A       = (float*)d_ws;                    // N*CH  (hs1)
    float* C       = A + (size_t)N * CH;              // N*CH  (hs2); ebuf aliases
    unsigned int* ebuf = (unsigned int*)C;            // E uints, dead before C live
    float* dinv    = C + (size_t)N * CH;              // N
    int*   row_ptr = (int*)(dinv + Npad);             // N+1
    int*   col     = row_ptr + Npad;                  // E
    int*   blkhist = col + Epad;                      // NBLK_P*NBUCK
    int*   off     = blkhist + NBLK_P * NBUCK;        // NBLK_P*NBUCK
    int*   bbase   = off + NBLK_P * NBUCK;            // NBUCK+1

    const int TB = 256;
    const int GRID = 2048;
    const int NB_USED = (N + BMASK) >> BSHIFT;        // buckets actually holding nodes

    // CSR build — scatter-free
    k_hist<<<NBLK_P, TB, 0, stream>>>(dst, blkhist, E);
    k_scan2<<<1, NBUCK, 0, stream>>>(blkhist, off, bbase, row_ptr, N);
    k_partition<<<NBLK_P, TB, 0, stream>>>(src, dst, off, ebuf, E);
    k_bucket_csr<<<NB_USED, 128, 0, stream>>>(ebuf, bbase, row_ptr, dinv, col, N);

    // Layer 1: A = (x @ W1) * dinv
    k_gemm64<<<GRID, TB, 0, stream>>>(x, W1, dinv, A, N);

    // Layer 2 fused: gather(A) -> relu(agg1+b1) @ W2 * dinv -> C
    k_gather_gemm<<<GRID, TB, 0, stream>>>(row_ptr, col, A, dinv, W2, b1, C, N);

    // Head fused: gather(C) -> sigmoid((agg2+b2)@Wl+bl) -> out
    k_gather_head<<<GRID, TB, 0, stream>>>(row_ptr, col, C, dinv, b2, Wl, bl, out, N);
}

// Round 5
// 383.217 us; speedup vs baseline: 2.6422x; 1.1119x over previous
//
#include <hip/hip_runtime.h>

#define CH 64
#define NBUCK 1024        // buckets = dst >> 7 (128 nodes/bucket); needs N <= 131072
#define BSHIFT 7
#define BMASK 127
#define NBLK_P 128        // partition blocks; must match between k_hist/k_partition

// ---- CSR build: scatter-free two-level bucket sort ------------------------

__global__ __launch_bounds__(256) void k_hist(const int* __restrict__ dst,
                                              int* __restrict__ blkhist, int E) {
    __shared__ int h[NBUCK];
    for (int i = threadIdx.x; i < NBUCK; i += blockDim.x) h[i] = 0;
    __syncthreads();
    int chunk = (E + NBLK_P - 1) / NBLK_P;
    int beg = blockIdx.x * chunk;
    int end = min(beg + chunk, E);
    for (int e = beg + threadIdx.x; e < end; e += blockDim.x)
        atomicAdd(&h[dst[e] >> BSHIFT], 1);
    __syncthreads();
    for (int i = threadIdx.x; i < NBUCK; i += blockDim.x)
        blkhist[blockIdx.x * NBUCK + i] = h[i];
}

__global__ __launch_bounds__(1024) void k_scan2(const int* __restrict__ blkhist,
                                                int* __restrict__ off,
                                                int* __restrict__ bbase,
                                                int* __restrict__ row_ptr, int n) {
    __shared__ int sh[NBUCK];
    int t = threadIdx.x;
    int tot = 0;
    for (int b = 0; b < NBLK_P; ++b) tot += blkhist[b * NBUCK + t];
    sh[t] = tot;
    __syncthreads();
    for (int o = 1; o < NBUCK; o <<= 1) {
        int v = (t >= o) ? sh[t - o] : 0;
        __syncthreads();
        sh[t] += v;
        __syncthreads();
    }
    int excl = sh[t] - tot;
    bbase[t] = excl;
    if (t == NBUCK - 1) {
        bbase[NBUCK] = sh[NBUCK - 1];       // = E
        row_ptr[n]   = sh[NBUCK - 1];       // CSR terminator
    }
    int run = excl;
    for (int b = 0; b < NBLK_P; ++b) {
        off[b * NBUCK + t] = run;
        run += blkhist[b * NBUCK + t];
    }
}

__global__ __launch_bounds__(256) void k_partition(const int* __restrict__ src,
                                                   const int* __restrict__ dst,
                                                   const int* __restrict__ off,
                                                   unsigned int* __restrict__ ebuf, int E) {
    __shared__ int cur[NBUCK];
    for (int i = threadIdx.x; i < NBUCK; i += blockDim.x)
        cur[i] = off[blockIdx.x * NBUCK + i];
    __syncthreads();
    int chunk = (E + NBLK_P - 1) / NBLK_P;
    int beg = blockIdx.x * chunk;
    int end = min(beg + chunk, E);
    for (int e = beg + threadIdx.x; e < end; e += blockDim.x) {
        int s = src[e];
        int d = dst[e];
        int p = atomicAdd(&cur[d >> BSHIFT], 1);
        ebuf[p] = ((unsigned int)(d & BMASK) << 17) | (unsigned int)s;
    }
}

__global__ __launch_bounds__(128) void k_bucket_csr(const unsigned int* __restrict__ ebuf,
                                                    const int* __restrict__ bbase,
                                                    int* __restrict__ row_ptr,
                                                    float* __restrict__ dinv,
                                                    int* __restrict__ col, int n) {
    __shared__ int cnt[128];
    __shared__ int cur[128];
    __shared__ int sc[128];
    int t = threadIdx.x;
    int k = blockIdx.x;
    int e0 = bbase[k], e1 = bbase[k + 1];
    cnt[t] = 0;
    __syncthreads();
    for (int e = e0 + t; e < e1; e += 128)
        atomicAdd(&cnt[ebuf[e] >> 17], 1);
    __syncthreads();
    int c = cnt[t];
    sc[t] = c;
    __syncthreads();
    for (int o = 1; o < 128; o <<= 1) {
        int v = (t >= o) ? sc[t - o] : 0;
        __syncthreads();
        sc[t] += v;
        __syncthreads();
    }
    int excl = sc[t] - c;
    int node = (k << BSHIFT) + t;
    if (node < n) {
        row_ptr[node] = e0 + excl;
        dinv[node] = rsqrtf((float)(c + 1));   // +1 self-loop
    }
    cur[t] = e0 + excl;
    __syncthreads();
    for (int e = e0 + t; e < e1; e += 128) {
        unsigned int u = ebuf[e];
        int p = atomicAdd(&cur[u >> 17], 1);
        col[p] = (int)(u & 0x1FFFFu);
    }
}

// ---- GEMM: wave-per-node, W in LDS, x-row broadcast via shuffle -----------
// Writes hs[node][c] = (in @ W)[node][c] * dinv[node].

__global__ __launch_bounds__(256) void k_gemm64(const float* __restrict__ in,
                                                const float* __restrict__ W,
                                                const float* __restrict__ dinv,
                                                float* __restrict__ hs, int n) {
    __shared__ float Ws[CH * CH];
    for (int i = threadIdx.x; i < CH * CH; i += blockDim.x) Ws[i] = W[i];
    __syncthreads();

    int lane = threadIdx.x & 63;
    int wid  = (blockIdx.x * blockDim.x + threadIdx.x) >> 6;
    int nw   = (gridDim.x * blockDim.x) >> 6;

    for (int node = wid; node < n; node += nw) {
        float v = in[(size_t)node * CH + lane];
        float acc = 0.0f;
#pragma unroll
        for (int k = 0; k < CH; ++k)
            acc = fmaf(__shfl(v, k, 64), Ws[k * CH + lane], acc);
        hs[(size_t)node * CH + lane] = acc * dinv[node];
    }
}

// ---- fused: gather(agg1) + bias + relu + GEMM(W2) + dot(Wl) -> z ----------
// z[node] = (((relu(dinv*(hs1[n]+sum hs1[s]) + b1)) @ W2) * dinv[n]) . Wl

__global__ __launch_bounds__(256) void k_gather_gemm(const int* __restrict__ row_ptr,
                                                     const int* __restrict__ col,
                                                     const float* __restrict__ hs,
                                                     const float* __restrict__ dinv,
                                                     const float* __restrict__ W,
                                                     const float* __restrict__ bias,
                                                     const float* __restrict__ Wl,
                                                     float* __restrict__ z, int n) {
    __shared__ float Ws[CH * CH];
    for (int i = threadIdx.x; i < CH * CH; i += blockDim.x) Ws[i] = W[i];
    __syncthreads();

    int lane = threadIdx.x & 63;
    int wid  = (blockIdx.x * blockDim.x + threadIdx.x) >> 6;
    int nw   = (gridDim.x * blockDim.x) >> 6;
    float wl = Wl[lane];
    float bi = bias[lane];

    for (int node = wid; node < n; node += nw) {
        int beg = row_ptr[node];
        int end = row_ptr[node + 1];
        float acc = hs[(size_t)node * CH + lane];  // self-loop term

        // lane-parallel index chunks: one coalesced 64-wide col load,
        // then shfl-broadcast 8 indices/group -> 8 independent row loads.
        int e = beg;
        while (e < end) {
            int m = end - e;
            if (m > 64) m = 64;
            int idx = (lane < m) ? col[e + lane] : 0;
            int j = 0;
            for (; j + 8 <= m; j += 8) {
                int s0 = __shfl(idx, j + 0, 64);
                int s1 = __shfl(idx, j + 1, 64);
                int s2 = __shfl(idx, j + 2, 64);
                int s3 = __shfl(idx, j + 3, 64);
                int s4 = __shfl(idx, j + 4, 64);
                int s5 = __shfl(idx, j + 5, 64);
                int s6 = __shfl(idx, j + 6, 64);
                int s7 = __shfl(idx, j + 7, 64);
                float a0 = hs[(size_t)s0 * CH + lane];
                float a1 = hs[(size_t)s1 * CH + lane];
                float a2 = hs[(size_t)s2 * CH + lane];
                float a3 = hs[(size_t)s3 * CH + lane];
                float a4 = hs[(size_t)s4 * CH + lane];
                float a5 = hs[(size_t)s5 * CH + lane];
                float a6 = hs[(size_t)s6 * CH + lane];
                float a7 = hs[(size_t)s7 * CH + lane];
                acc += a0; acc += a1; acc += a2; acc += a3;
                acc += a4; acc += a5; acc += a6; acc += a7;
            }
            for (; j < m; ++j) {
                int s = __shfl(idx, j, 64);
                acc += hs[(size_t)s * CH + lane];
            }
            e += m;
        }

        float d = dinv[node];
        float v = fmaxf(acc * d + bi, 0.0f);       // h1 row = relu(agg1 + b1)
        float acc2 = 0.0f;
#pragma unroll
        for (int k = 0; k < CH; ++k)
            acc2 = fmaf(__shfl(v, k, 64), Ws[k * CH + lane], acc2);
        // z = (acc2 * d) . Wl   (wave reduction)
        float p = acc2 * d * wl;
#pragma unroll
        for (int o = 32; o > 0; o >>= 1) p += __shfl_xor(p, o, 64);
        if (lane == 0) z[node] = p;
    }
}

// ---- head: out[n] = sigmoid(dinv[n]*(z[n]+sum z[s]) + (b2.Wl + bl)) -------
// Scalar gather over 400KB L2-resident z. Thread-per-node.

__global__ __launch_bounds__(256) void k_head(const int* __restrict__ row_ptr,
                                              const int* __restrict__ col,
                                              const float* __restrict__ z,
                                              const float* __restrict__ dinv,
                                              const float* __restrict__ b2,
                                              const float* __restrict__ Wl,
                                              const float* __restrict__ bl,
                                              float* __restrict__ out, int n) {
    int lane = threadIdx.x & 63;
    // wave-uniform constant c0 = b2 . Wl + bl
    float c0 = b2[lane] * Wl[lane];
#pragma unroll
    for (int o = 32; o > 0; o >>= 1) c0 += __shfl_xor(c0, o, 64);
    c0 += bl[0];

    int tid = blockIdx.x * blockDim.x + threadIdx.x;
    int st  = gridDim.x * blockDim.x;
    for (int node = tid; node < n; node += st) {
        int beg = row_ptr[node];
        int end = row_ptr[node + 1];
        float s = z[node];
        int e = beg;
        for (; e + 4 <= end; e += 4) {
            float t0 = z[col[e]];
            float t1 = z[col[e + 1]];
            float t2 = z[col[e + 2]];
            float t3 = z[col[e + 3]];
            s += t0; s += t1; s += t2; s += t3;
        }
        for (; e < end; ++e) s += z[col[e]];
        float v = dinv[node] * s + c0;
        out[node] = 1.0f / (1.0f + expf(-v));
    }
}

// ---- launch ---------------------------------------------------------------

extern "C" void kernel_launch(void* const* d_in, const int* in_sizes, int n_in,
                              void* d_out, int out_size, void* d_ws, size_t ws_size,
                              hipStream_t stream) {
    const float* x   = (const float*)d_in[0];
    const int*   ei  = (const int*)d_in[1];   // [2, E] row-major
    const float* W1  = (const float*)d_in[2];
    const float* b1  = (const float*)d_in[3];
    const float* W2  = (const float*)d_in[4];
    const float* b2  = (const float*)d_in[5];
    const float* Wl  = (const float*)d_in[6];
    const float* bl  = (const float*)d_in[7];
    float*       out = (float*)d_out;

    const int N = in_sizes[0] / CH;
    const int E = in_sizes[1] / 2;
    const int* src = ei;
    const int* dst = ei + E;

    const size_t Npad = ((size_t)N + 511) & ~(size_t)511;
    const size_t Epad = ((size_t)E + 511) & ~(size_t)511;

    float* A       = (float*)d_ws;                    // N*CH  (hs1)
    float* z       = A + (size_t)N * CH;              // N     (scalar head input)
    float* dinv    = z + Npad;                        // N
    int*   row_ptr = (int*)(dinv + Npad);             // N+1
    int*   col     = row_ptr + Npad;                  // E
    unsigned int* ebuf = (unsigned int*)(col + Epad); // E
    int*   blkhist = (int*)(ebuf + Epad);             // NBLK_P*NBUCK
    int*   off     = blkhist + NBLK_P * NBUCK;        // NBLK_P*NBUCK
    int*   bbase   = off + NBLK_P * NBUCK;            // NBUCK+1

    const int TB = 256;
    const int GRID = 2048;
    const int NB_USED = (N + BMASK) >> BSHIFT;

    // CSR build — scatter-free
    k_hist<<<NBLK_P, TB, 0, stream>>>(dst, blkhist, E);
    k_scan2<<<1, NBUCK, 0, stream>>>(blkhist, off, bbase, row_ptr, N);
    k_partition<<<NBLK_P, TB, 0, stream>>>(src, dst, off, ebuf, E);
    k_bucket_csr<<<NB_USED, 128, 0, stream>>>(ebuf, bbase, row_ptr, dinv, col, N);

    // Layer 1: A = (x @ W1) * dinv
    k_gemm64<<<GRID, TB, 0, stream>>>(x, W1, dinv, A, N);

    // Layer 2 fused: gather(A) -> relu(agg1+b1) @ W2 * dinv -> dot(Wl) -> z
    k_gather_gemm<<<GRID, TB, 0, stream>>>(row_ptr, col, A, dinv, W2, b1, Wl, z, N);

    // Head: scalar gather over z + sigmoid
    k_head<<<(N + TB - 1) / TB, TB, 0, stream>>>(row_ptr, col, z, dinv, b2, Wl, bl, out, N);
}